// Round 10
// baseline (979.433 us; speedup 1.0000x reference)
//
#include <hip/hip_runtime.h>

typedef unsigned short u16;
typedef __bf16 bf16x8 __attribute__((ext_vector_type(8)));
typedef unsigned short u16x8 __attribute__((ext_vector_type(8)));
typedef float f32x4 __attribute__((ext_vector_type(4)));

#define GLDS16(gp, lp)                                                        \
  __builtin_amdgcn_global_load_lds(                                           \
      (const __attribute__((address_space(1))) void*)(gp),                    \
      (__attribute__((address_space(3))) void*)(lp), 16, 0, 0)

__device__ __forceinline__ u16 f2bf(float f) {
  unsigned u = __float_as_uint(f);
  u += 0x7FFFu + ((u >> 16) & 1u);
  return (u16)(u >> 16);
}

__device__ __forceinline__ f32x4 mfma_bf16(bf16x8 a, bf16x8 b, f32x4 c) {
  return __builtin_amdgcn_mfma_f32_16x16x32_bf16(a, b, c, 0, 0, 0);
}

// ---------------------------------------------------------------- convert
__global__ void cvt_f32_bf16(const float* __restrict__ src,
                             u16* __restrict__ dst, int n8) {
  for (int i = blockIdx.x * blockDim.x + threadIdx.x; i < n8;
       i += gridDim.x * blockDim.x) {
    const float4* sp = (const float4*)src + (size_t)i * 2;
    float4 a = sp[0], b = sp[1];
    u16x8 o;
    o[0] = f2bf(a.x); o[1] = f2bf(a.y); o[2] = f2bf(a.z); o[3] = f2bf(a.w);
    o[4] = f2bf(b.x); o[5] = f2bf(b.y); o[6] = f2bf(b.z); o[7] = f2bf(b.w);
    *((u16x8*)dst + i) = o;
  }
}

// ------------------------------------------------------- GEMM (8-phase 256²)
// (unchanged — proven)
template <int OUT_BF16>
__global__ __launch_bounds__(512, 2) void gemm8p(const u16* __restrict__ A,
                                                 const u16* __restrict__ B,
                                                 const float* __restrict__ bias,
                                                 void* __restrict__ Cout,
                                                 int M, int N, int K, int nbm) {
  __shared__ __attribute__((aligned(16))) u16 L[2][4][8192];
  const int t = threadIdx.x, lane = t & 63, w = t >> 6;
  const int l15 = lane & 15, l4 = lane >> 4;
  const int wm = w >> 2, wn = w & 3;

  const int cpx = (int)gridDim.x >> 3;
  const int wg = (int)blockIdx.x;
  const int swz = (wg & 7) * cpx + (wg >> 3);
  const int bm = (swz % nbm) * 256;
  const int bn = (swz / nbm) * 256;

  const size_t aoff = (size_t)(t >> 3) * K + (((t & 7) ^ ((t >> 3) & 7)) << 3);
  const u16* SB[4] = {A + (size_t)bm * K, A + (size_t)(bm + 128) * K,
                      B + (size_t)bn * K, B + (size_t)(bn + 128) * K};
  const int ldst = w << 9;

#define STG(d, s, l, kt)                                                      \
  GLDS16(SB[s] + (size_t)(l) * 64 * K + (size_t)(kt) * 64 + aoff,             \
         &L[d][s][(l) * 4096 + ldst])
#define BAR __builtin_amdgcn_s_barrier()
#define WAITL asm volatile("s_waitcnt lgkmcnt(0)" ::: "memory")

  f32x4 acc[8][4];
  f32x4 z4 = {0.f, 0.f, 0.f, 0.f};
#pragma unroll
  for (int i = 0; i < 8; ++i)
#pragma unroll
    for (int j = 0; j < 4; ++j) acc[i][j] = z4;

  const u16* AH[2] = {&L[0][wm][0], &L[1][wm][0]};
  const u16* BH[2] = {&L[0][2 + (wn >> 1)][0], &L[1][2 + (wn >> 1)][0]};
  const int cb = (wn & 1) * 64;

  bf16x8 af[4][2], bfr[4][2];

  auto rdA = [&](const u16* H, int mh) {
#pragma unroll
    for (int m2 = 0; m2 < 4; ++m2) {
      int ra = mh * 64 + m2 * 16 + l15;
      const u16* p = H + ra * 64;
      af[m2][0] = *(const bf16x8*)(p + ((l4 ^ (ra & 7)) << 3));
      af[m2][1] = *(const bf16x8*)(p + (((4 + l4) ^ (ra & 7)) << 3));
    }
  };
  auto rdB = [&](const u16* H, int nh) {
#pragma unroll
    for (int n2 = 0; n2 < 2; ++n2) {
      int rb = cb + (nh * 2 + n2) * 16 + l15;
      const u16* p = H + rb * 64;
      bfr[nh * 2 + n2][0] = *(const bf16x8*)(p + ((l4 ^ (rb & 7)) << 3));
      bfr[nh * 2 + n2][1] = *(const bf16x8*)(p + (((4 + l4) ^ (rb & 7)) << 3));
    }
  };
  auto mma = [&](int mh, int nh) {
    __builtin_amdgcn_s_setprio(1);
#pragma unroll
    for (int m2 = 0; m2 < 4; ++m2)
#pragma unroll
      for (int n2 = 0; n2 < 2; ++n2) {
        int ai = mh * 4 + m2, bi = nh * 2 + n2;
        acc[ai][bi] = mfma_bf16(af[m2][0], bfr[bi][0], acc[ai][bi]);
        acc[ai][bi] = mfma_bf16(af[m2][1], bfr[bi][1], acc[ai][bi]);
      }
    __builtin_amdgcn_s_setprio(0);
  };

  STG(0, 0, 0, 0); STG(0, 0, 1, 0); STG(0, 1, 0, 0); STG(0, 1, 1, 0);
  STG(0, 2, 0, 0); STG(0, 2, 1, 0); STG(0, 3, 0, 0); STG(0, 3, 1, 0);
  STG(1, 0, 0, 1); STG(1, 1, 0, 1); STG(1, 2, 0, 1); STG(1, 2, 1, 1);
  STG(1, 3, 0, 1); STG(1, 3, 1, 1);
  asm volatile("s_waitcnt vmcnt(0)" ::: "memory");
  BAR;

  const int NI = K >> 7;
  for (int i = 0; i < NI; ++i) {
    const int kt = 2 * i;
    const bool st = (i + 1 < NI);
    rdA(AH[0], 0); rdB(BH[0], 0);
    STG(1, 0, 1, kt + 1); STG(1, 1, 1, kt + 1);
    BAR; WAITL; mma(0, 0); BAR;
    rdB(BH[0], 1);
    if (st) { STG(0, 0, 0, kt + 2); STG(0, 1, 0, kt + 2); }
    BAR; WAITL; mma(0, 1); BAR;
    rdA(AH[0], 1);
    if (st) { STG(0, 2, 0, kt + 2); STG(0, 2, 1, kt + 2); }
    BAR; WAITL; mma(1, 1); BAR;
    if (st) {
      STG(0, 3, 0, kt + 2); STG(0, 3, 1, kt + 2);
      asm volatile("s_waitcnt vmcnt(6)" ::: "memory");
    } else {
      asm volatile("s_waitcnt vmcnt(0)" ::: "memory");
    }
    BAR; mma(1, 0); BAR;
    rdA(AH[1], 0); rdB(BH[1], 0);
    if (st) { STG(0, 0, 1, kt + 2); STG(0, 1, 1, kt + 2); }
    BAR; WAITL; mma(0, 0); BAR;
    rdB(BH[1], 1);
    if (st) { STG(1, 0, 0, kt + 3); STG(1, 1, 0, kt + 3); }
    BAR; WAITL; mma(0, 1); BAR;
    rdA(AH[1], 1);
    if (st) { STG(1, 2, 0, kt + 3); STG(1, 2, 1, kt + 3); }
    BAR; WAITL; mma(1, 1); BAR;
    if (st) {
      STG(1, 3, 0, kt + 3); STG(1, 3, 1, kt + 3);
      asm volatile("s_waitcnt vmcnt(6)" ::: "memory");
    }
    BAR; mma(1, 0); BAR;
  }
#undef STG
#undef BAR
#undef WAITL

  const int cr = l4 * 4;
#pragma unroll
  for (int ni = 0; ni < 4; ++ni) {
    int col = bn + wn * 64 + ni * 16 + l15;
    float bv = bias[col];
#pragma unroll
    for (int mi = 0; mi < 8; ++mi) {
      int row = bm + wm * 128 + mi * 16 + cr;
#pragma unroll
      for (int r = 0; r < 4; ++r) {
        float v = acc[mi][ni][r] + bv;
        if (OUT_BF16)
          ((u16*)Cout)[(size_t)(row + r) * N + col] = f2bf(v);
        else
          ((float*)Cout)[(size_t)(row + r) * N + col] = v;
      }
    }
  }
}

// -------------------------------------------------------------- attention
// 48KB LDS (3 blocks/CU): single-buffered Ks/Vt, reg-staged K+V, 2 barriers
// per tile, loads issued mid-tile (covered by PV). 1024 blocks, LPT order.
__device__ __forceinline__ int vt_idx(int d, int kk) {
  int swz = (d ^ (d >> 3)) & 7;
  return d * 64 + ((((kk >> 3) ^ swz) << 3) | (kk & 7));
}
__device__ __forceinline__ int ps_idx(int r, int c) {
  return r * 64 + ((((c >> 3) ^ ((r >> 2) & 7)) << 3) | (c & 7));
}

__global__ __launch_bounds__(256, 3) void attn_fwd(const u16* __restrict__ qkv,
                                                   u16* __restrict__ ctx) {
  constexpr int NQ = 6144, SD = 2048;
  __shared__ __attribute__((aligned(16))) u16 Ks[64 * 128];   // 16KB
  __shared__ __attribute__((aligned(16))) u16 Vt[128 * 64];   // 16KB
  __shared__ __attribute__((aligned(16))) u16 Ps[128 * 64];   // 16KB
  const int t = threadIdx.x, lane = t & 63, w = t >> 6;
  const int l15 = lane & 15, l4 = lane >> 4;

  // LPT dispatch: heavy q-tiles (qt=15) get the lowest block ids
  const int L = (int)blockIdx.x;
  const int qt = 15 - (L >> 6);
  const int h = L & 15, b = (L >> 4) & 3;
  const size_t rowbase = (size_t)b * 2048;
  const int hq = h * 384;
  const int q0 = qt * 128;
  const int nt = 2 * qt + 2;
  const int qr0 = q0 + w * 32 + l4 * 4;  // + mi*16 + r

  // K stage: thread covers row (t>>4)+i*16, 16B slot t&15 (linear global;
  // swizzle applied on the LDS write -> read addressing unchanged)
  const u16* KgR =
      qkv + (rowbase + (t >> 4)) * NQ + hq + 128 + ((t & 15) << 3);
  const int krow0 = t >> 4;
  const int kslot = ((t & 15) ^ ((t >> 4) & 7)) << 3;  // row&7 == (t>>4)&7
  // V stage (proven): thread covers row (t&15)+p*16, d-chunk (t>>4)*8
  const u16* Vg = qkv + (rowbase + (t & 15)) * NQ + hq + 256 + ((t >> 4) << 3);
  const int vkk = t & 15, vd0 = (t >> 4) << 3;

  const float C = 0.12751879522447905f;   // (1/sqrt(128)) * log2(e)
  const float THRC = 62.73592239488341f;  // 8 / C

  bf16x8 qf[2][4];
#pragma unroll
  for (int mi = 0; mi < 2; ++mi) {
    const u16* qp =
        qkv + (rowbase + q0 + w * 32 + mi * 16 + l15) * NQ + hq + l4 * 8;
#pragma unroll
    for (int kc = 0; kc < 4; ++kc) qf[mi][kc] = *(const bf16x8*)(qp + kc * 32);
  }

  f32x4 z4 = {0.f, 0.f, 0.f, 0.f};
  f32x4 oacc[2][8];
#pragma unroll
  for (int mi = 0; mi < 2; ++mi)
#pragma unroll
    for (int i = 0; i < 8; ++i) oacc[mi][i] = z4;
  float m_run[2][4], l_run[2][4];
#pragma unroll
  for (int mi = 0; mi < 2; ++mi)
#pragma unroll
    for (int r = 0; r < 4; ++r) { m_run[mi][r] = -3.0e38f; l_run[mi][r] = 0.f; }

  // ---- prologue: load + scatter tile 0 (fresh LDS, no prior readers)
  u16x8 kA[4], vA[4];
#pragma unroll
  for (int i = 0; i < 4; ++i)
    kA[i] = *(const u16x8*)(KgR + (size_t)(i * 16) * NQ);
#pragma unroll
  for (int p = 0; p < 4; ++p)
    vA[p] = *(const u16x8*)(Vg + (size_t)(p * 16) * NQ);
#pragma unroll
  for (int i = 0; i < 4; ++i)
    *(u16x8*)(Ks + (i * 16 + krow0) * 128 + kslot) = kA[i];
#pragma unroll
  for (int p = 0; p < 4; ++p) {
    int kk = p * 16 + vkk;
#pragma unroll
    for (int j = 0; j < 8; ++j) Vt[vt_idx(vd0 + j, kk)] = vA[p][j];
  }
  __syncthreads();  // publish tile 0

  for (int tt = 0; tt < nt; ++tt) {
    const int k0 = tt * 64;
    const bool more = (tt + 1 < nt);

    // S = Q K^T
    f32x4 sc[2][4];
#pragma unroll
    for (int mi = 0; mi < 2; ++mi)
#pragma unroll
      for (int nf = 0; nf < 4; ++nf) sc[mi][nf] = z4;
#pragma unroll
    for (int kc = 0; kc < 4; ++kc)
#pragma unroll
      for (int nf = 0; nf < 4; ++nf) {
        int rk = nf * 16 + l15;
        bf16x8 kf = *(const bf16x8*)(Ks + rk * 128 +
                                     (((kc * 4 + l4) ^ (rk & 7)) << 3));
        sc[0][nf] = mfma_bf16(qf[0][kc], kf, sc[0][nf]);
        sc[1][nf] = mfma_bf16(qf[1][kc], kf, sc[1][nf]);
      }
    // causal mask: only the last two tiles are partial
    if (tt + 2 >= nt) {
#pragma unroll
      for (int mi = 0; mi < 2; ++mi)
#pragma unroll
        for (int nf = 0; nf < 4; ++nf) {
          int col = k0 + nf * 16 + l15;
          int qr = qr0 + mi * 16;
#pragma unroll
          for (int r = 0; r < 4; ++r)
            if (col > qr + r) sc[mi][nf][r] = -3.0e38f;
        }
    }
    // row max over 16 col-lanes
    float mx[2][4];
#pragma unroll
    for (int mi = 0; mi < 2; ++mi)
#pragma unroll
      for (int r = 0; r < 4; ++r)
        mx[mi][r] = fmaxf(fmaxf(sc[mi][0][r], sc[mi][1][r]),
                          fmaxf(sc[mi][2][r], sc[mi][3][r]));
#pragma unroll
    for (int off = 8; off >= 1; off >>= 1)
#pragma unroll
      for (int mi = 0; mi < 2; ++mi)
#pragma unroll
        for (int r = 0; r < 4; ++r)
          mx[mi][r] = fmaxf(mx[mi][r], __shfl_xor(mx[mi][r], off));
    // defer-max rescale
    bool upd = false;
#pragma unroll
    for (int mi = 0; mi < 2; ++mi)
#pragma unroll
      for (int r = 0; r < 4; ++r) upd |= (mx[mi][r] > m_run[mi][r] + THRC);
    if (__any(upd)) {
#pragma unroll
      for (int mi = 0; mi < 2; ++mi)
#pragma unroll
        for (int r = 0; r < 4; ++r) {
          float mn = fmaxf(m_run[mi][r], mx[mi][r]);
          float cr = exp2f((m_run[mi][r] - mn) * C);
          m_run[mi][r] = mn;
          l_run[mi][r] *= cr;
#pragma unroll
          for (int nf = 0; nf < 8; ++nf) oacc[mi][nf][r] *= cr;
        }
    }
    // P = exp2(S*C - m*C); row sums; Ps writes
#pragma unroll
    for (int mi = 0; mi < 2; ++mi) {
      float mC[4], sm[4];
#pragma unroll
      for (int r = 0; r < 4; ++r) mC[r] = m_run[mi][r] * C;
#pragma unroll
      for (int nf = 0; nf < 4; ++nf)
#pragma unroll
        for (int r = 0; r < 4; ++r)
          sc[mi][nf][r] = exp2f(fmaf(sc[mi][nf][r], C, -mC[r]));
#pragma unroll
      for (int r = 0; r < 4; ++r)
        sm[r] = (sc[mi][0][r] + sc[mi][1][r]) + (sc[mi][2][r] + sc[mi][3][r]);
#pragma unroll
      for (int off = 8; off >= 1; off >>= 1)
#pragma unroll
        for (int r = 0; r < 4; ++r) sm[r] += __shfl_xor(sm[r], off);
#pragma unroll
      for (int r = 0; r < 4; ++r) l_run[mi][r] += sm[r];
#pragma unroll
      for (int nf = 0; nf < 4; ++nf)
#pragma unroll
        for (int r = 0; r < 4; ++r)
          ((__bf16*)Ps)[ps_idx(w * 32 + mi * 16 + l4 * 4 + r,
                               nf * 16 + l15)] = (__bf16)sc[mi][nf][r];
    }
    // issue next-tile loads (consumed at scatter; covered by PV below)
    if (more) {
      const int knl = (tt + 1) * 64;
#pragma unroll
      for (int i = 0; i < 4; ++i)
        kA[i] = *(const u16x8*)(KgR + (size_t)(knl + i * 16) * NQ);
#pragma unroll
      for (int p = 0; p < 4; ++p)
        vA[p] = *(const u16x8*)(Vg + (size_t)(knl + p * 16) * NQ);
    }
    // O += P V
#pragma unroll
    for (int kc = 0; kc < 2; ++kc) {
      bf16x8 pf0 =
          *(const bf16x8*)(Ps + ps_idx(w * 32 + l15, kc * 32 + l4 * 8));
      bf16x8 pf1 =
          *(const bf16x8*)(Ps + ps_idx(w * 32 + 16 + l15, kc * 32 + l4 * 8));
#pragma unroll
      for (int nf = 0; nf < 8; ++nf) {
        bf16x8 vf =
            *(const bf16x8*)(Vt + vt_idx(nf * 16 + l15, kc * 32 + l4 * 8));
        oacc[0][nf] = mfma_bf16(pf0, vf, oacc[0][nf]);
        oacc[1][nf] = mfma_bf16(pf1, vf, oacc[1][nf]);
      }
    }
    if (more) {
      __syncthreads();  // all reads of Ks/Vt done (drains loads too)
#pragma unroll
      for (int i = 0; i < 4; ++i)
        *(u16x8*)(Ks + (i * 16 + krow0) * 128 + kslot) = kA[i];
#pragma unroll
      for (int p = 0; p < 4; ++p) {
        int kk = p * 16 + vkk;
#pragma unroll
        for (int j = 0; j < 8; ++j) Vt[vt_idx(vd0 + j, kk)] = vA[p][j];
      }
      __syncthreads();  // publish tile tt+1
    }
  }
  // normalize + store
#pragma unroll
  for (int mi = 0; mi < 2; ++mi) {
    float inv[4];
#pragma unroll
    for (int r = 0; r < 4; ++r) inv[r] = 1.f / l_run[mi][r];
    u16* cp = ctx + (rowbase + q0 + w * 32 + mi * 16 + l4 * 4) * SD +
              h * 128 + l15;
#pragma unroll
    for (int nf = 0; nf < 8; ++nf)
#pragma unroll
      for (int r = 0; r < 4; ++r)
        ((__bf16*)cp)[(size_t)r * SD + nf * 16] =
            (__bf16)(oacc[mi][nf][r] * inv[r]);
  }
}

// ----------------------------------------------------------------- launch
extern "C" void kernel_launch(void* const* d_in, const int* in_sizes, int n_in,
                              void* d_out, int out_size, void* d_ws,
                              size_t ws_size, hipStream_t stream) {
  const float* x = (const float*)d_in[0];
  const float* wqkv = (const float*)d_in[2];
  const float* bqkv = (const float*)d_in[3];
  const float* wout = (const float*)d_in[4];
  const float* bout = (const float*)d_in[5];
  float* out = (float*)d_out;
  char* ws = (char*)d_ws;

  u16* xb = (u16*)(ws);                  //  33,554,432  x bf16 (later: ctx)
  u16* wqkvb = (u16*)(ws + 33554432);    //  25,165,824  w_qkv bf16
  u16* woutb = (u16*)(ws + 58720256);    //   8,388,608  w_out bf16
  u16* qkvb = (u16*)(ws + 67108864);     // 100,663,296  qkv bf16
  u16* ctx = xb;                         // reuse (x dead after gemm1)

  cvt_f32_bf16<<<2048, 256, 0, stream>>>(x, xb, 16777216 / 8);
  cvt_f32_bf16<<<2048, 256, 0, stream>>>(wqkv, wqkvb, 12582912 / 8);
  cvt_f32_bf16<<<1024, 256, 0, stream>>>(wout, woutb, 4194304 / 8);
  gemm8p<1><<<dim3(32 * 24), 512, 0, stream>>>(xb, wqkvb, bqkv, qkvb, 8192,
                                               6144, 2048, 32);
  attn_fwd<<<dim3(1024), 256, 0, stream>>>(qkvb, ctx);
  gemm8p<0><<<dim3(32 * 8), 512, 0, stream>>>(ctx, woutb, bout, out, 8192,
                                              2048, 2048, 32);
}

// Round 11
// 627.435 us; speedup vs baseline: 1.5610x; 1.5610x over previous
//
#include <hip/hip_runtime.h>

typedef unsigned short u16;
typedef __bf16 bf16x8 __attribute__((ext_vector_type(8)));
typedef unsigned short u16x8 __attribute__((ext_vector_type(8)));
typedef float f32x4 __attribute__((ext_vector_type(4)));

#define GLDS16(gp, lp)                                                        \
  __builtin_amdgcn_global_load_lds(                                           \
      (const __attribute__((address_space(1))) void*)(gp),                    \
      (__attribute__((address_space(3))) void*)(lp), 16, 0, 0)

__device__ __forceinline__ u16 f2bf(float f) {
  unsigned u = __float_as_uint(f);
  u += 0x7FFFu + ((u >> 16) & 1u);
  return (u16)(u >> 16);
}

__device__ __forceinline__ f32x4 mfma_bf16(bf16x8 a, bf16x8 b, f32x4 c) {
  return __builtin_amdgcn_mfma_f32_16x16x32_bf16(a, b, c, 0, 0, 0);
}

// DPP lane-permute within 16-lane rows (VALU-only, replaces ds_bpermute)
template <int CTRL>
__device__ __forceinline__ float dppf(float x) {
  return __int_as_float(
      __builtin_amdgcn_mov_dpp(__float_as_int(x), CTRL, 0xF, 0xF, false));
}
// 16-lane reduction tree: quad xor1, quad xor2, half-mirror, mirror
__device__ __forceinline__ float dpp_max16(float x) {
  x = fmaxf(x, dppf<0xB1>(x));   // quad_perm [1,0,3,2]
  x = fmaxf(x, dppf<0x4E>(x));   // quad_perm [2,3,0,1]
  x = fmaxf(x, dppf<0x141>(x));  // row_half_mirror
  x = fmaxf(x, dppf<0x140>(x));  // row_mirror
  return x;
}
__device__ __forceinline__ float dpp_sum16(float x) {
  x += dppf<0xB1>(x);
  x += dppf<0x4E>(x);
  x += dppf<0x141>(x);
  x += dppf<0x140>(x);
  return x;
}

// ---------------------------------------------------------------- convert
__global__ void cvt_f32_bf16(const float* __restrict__ src,
                             u16* __restrict__ dst, int n8) {
  for (int i = blockIdx.x * blockDim.x + threadIdx.x; i < n8;
       i += gridDim.x * blockDim.x) {
    const float4* sp = (const float4*)src + (size_t)i * 2;
    float4 a = sp[0], b = sp[1];
    u16x8 o;
    o[0] = f2bf(a.x); o[1] = f2bf(a.y); o[2] = f2bf(a.z); o[3] = f2bf(a.w);
    o[4] = f2bf(b.x); o[5] = f2bf(b.y); o[6] = f2bf(b.z); o[7] = f2bf(b.w);
    *((u16x8*)dst + i) = o;
  }
}

// ------------------------------------------------------- GEMM (8-phase 256²)
// (unchanged — proven)
template <int OUT_BF16>
__global__ __launch_bounds__(512, 2) void gemm8p(const u16* __restrict__ A,
                                                 const u16* __restrict__ B,
                                                 const float* __restrict__ bias,
                                                 void* __restrict__ Cout,
                                                 int M, int N, int K, int nbm) {
  __shared__ __attribute__((aligned(16))) u16 L[2][4][8192];
  const int t = threadIdx.x, lane = t & 63, w = t >> 6;
  const int l15 = lane & 15, l4 = lane >> 4;
  const int wm = w >> 2, wn = w & 3;

  const int cpx = (int)gridDim.x >> 3;
  const int wg = (int)blockIdx.x;
  const int swz = (wg & 7) * cpx + (wg >> 3);
  const int bm = (swz % nbm) * 256;
  const int bn = (swz / nbm) * 256;

  const size_t aoff = (size_t)(t >> 3) * K + (((t & 7) ^ ((t >> 3) & 7)) << 3);
  const u16* SB[4] = {A + (size_t)bm * K, A + (size_t)(bm + 128) * K,
                      B + (size_t)bn * K, B + (size_t)(bn + 128) * K};
  const int ldst = w << 9;

#define STG(d, s, l, kt)                                                      \
  GLDS16(SB[s] + (size_t)(l) * 64 * K + (size_t)(kt) * 64 + aoff,             \
         &L[d][s][(l) * 4096 + ldst])
#define BAR __builtin_amdgcn_s_barrier()
#define WAITL asm volatile("s_waitcnt lgkmcnt(0)" ::: "memory")

  f32x4 acc[8][4];
  f32x4 z4 = {0.f, 0.f, 0.f, 0.f};
#pragma unroll
  for (int i = 0; i < 8; ++i)
#pragma unroll
    for (int j = 0; j < 4; ++j) acc[i][j] = z4;

  const u16* AH[2] = {&L[0][wm][0], &L[1][wm][0]};
  const u16* BH[2] = {&L[0][2 + (wn >> 1)][0], &L[1][2 + (wn >> 1)][0]};
  const int cb = (wn & 1) * 64;

  bf16x8 af[4][2], bfr[4][2];

  auto rdA = [&](const u16* H, int mh) {
#pragma unroll
    for (int m2 = 0; m2 < 4; ++m2) {
      int ra = mh * 64 + m2 * 16 + l15;
      const u16* p = H + ra * 64;
      af[m2][0] = *(const bf16x8*)(p + ((l4 ^ (ra & 7)) << 3));
      af[m2][1] = *(const bf16x8*)(p + (((4 + l4) ^ (ra & 7)) << 3));
    }
  };
  auto rdB = [&](const u16* H, int nh) {
#pragma unroll
    for (int n2 = 0; n2 < 2; ++n2) {
      int rb = cb + (nh * 2 + n2) * 16 + l15;
      const u16* p = H + rb * 64;
      bfr[nh * 2 + n2][0] = *(const bf16x8*)(p + ((l4 ^ (rb & 7)) << 3));
      bfr[nh * 2 + n2][1] = *(const bf16x8*)(p + (((4 + l4) ^ (rb & 7)) << 3));
    }
  };
  auto mma = [&](int mh, int nh) {
    __builtin_amdgcn_s_setprio(1);
#pragma unroll
    for (int m2 = 0; m2 < 4; ++m2)
#pragma unroll
      for (int n2 = 0; n2 < 2; ++n2) {
        int ai = mh * 4 + m2, bi = nh * 2 + n2;
        acc[ai][bi] = mfma_bf16(af[m2][0], bfr[bi][0], acc[ai][bi]);
        acc[ai][bi] = mfma_bf16(af[m2][1], bfr[bi][1], acc[ai][bi]);
      }
    __builtin_amdgcn_s_setprio(0);
  };

  STG(0, 0, 0, 0); STG(0, 0, 1, 0); STG(0, 1, 0, 0); STG(0, 1, 1, 0);
  STG(0, 2, 0, 0); STG(0, 2, 1, 0); STG(0, 3, 0, 0); STG(0, 3, 1, 0);
  STG(1, 0, 0, 1); STG(1, 1, 0, 1); STG(1, 2, 0, 1); STG(1, 2, 1, 1);
  STG(1, 3, 0, 1); STG(1, 3, 1, 1);
  asm volatile("s_waitcnt vmcnt(0)" ::: "memory");
  BAR;

  const int NI = K >> 7;
  for (int i = 0; i < NI; ++i) {
    const int kt = 2 * i;
    const bool st = (i + 1 < NI);
    rdA(AH[0], 0); rdB(BH[0], 0);
    STG(1, 0, 1, kt + 1); STG(1, 1, 1, kt + 1);
    BAR; WAITL; mma(0, 0); BAR;
    rdB(BH[0], 1);
    if (st) { STG(0, 0, 0, kt + 2); STG(0, 1, 0, kt + 2); }
    BAR; WAITL; mma(0, 1); BAR;
    rdA(AH[0], 1);
    if (st) { STG(0, 2, 0, kt + 2); STG(0, 2, 1, kt + 2); }
    BAR; WAITL; mma(1, 1); BAR;
    if (st) {
      STG(0, 3, 0, kt + 2); STG(0, 3, 1, kt + 2);
      asm volatile("s_waitcnt vmcnt(6)" ::: "memory");
    } else {
      asm volatile("s_waitcnt vmcnt(0)" ::: "memory");
    }
    BAR; mma(1, 0); BAR;
    rdA(AH[1], 0); rdB(BH[1], 0);
    if (st) { STG(0, 0, 1, kt + 2); STG(0, 1, 1, kt + 2); }
    BAR; WAITL; mma(0, 0); BAR;
    rdB(BH[1], 1);
    if (st) { STG(1, 0, 0, kt + 3); STG(1, 1, 0, kt + 3); }
    BAR; WAITL; mma(0, 1); BAR;
    rdA(AH[1], 1);
    if (st) { STG(1, 2, 0, kt + 3); STG(1, 2, 1, kt + 3); }
    BAR; WAITL; mma(1, 1); BAR;
    if (st) {
      STG(1, 3, 0, kt + 3); STG(1, 3, 1, kt + 3);
      asm volatile("s_waitcnt vmcnt(6)" ::: "memory");
    }
    BAR; mma(1, 0); BAR;
  }
#undef STG
#undef BAR
#undef WAITL

  const int cr = l4 * 4;
#pragma unroll
  for (int ni = 0; ni < 4; ++ni) {
    int col = bn + wn * 64 + ni * 16 + l15;
    float bv = bias[col];
#pragma unroll
    for (int mi = 0; mi < 8; ++mi) {
      int row = bm + wm * 128 + mi * 16 + cr;
#pragma unroll
      for (int r = 0; r < 4; ++r) {
        float v = acc[mi][ni][r] + bv;
        if (OUT_BF16)
          ((u16*)Cout)[(size_t)(row + r) * N + col] = f2bf(v);
        else
          ((float*)Cout)[(size_t)(row + r) * N + col] = v;
      }
    }
  }
}

// -------------------------------------------------------------- attention
// Round-4 proven structure (dbuf 80KB, (8,16,4) grid, pairing) with ONE
// change: softmax row-reductions via DPP (VALU) instead of ds_bpermute.
__device__ __forceinline__ int vt_idx(int d, int kk) {
  int swz = (d ^ (d >> 3)) & 7;
  return d * 64 + ((((kk >> 3) ^ swz) << 3) | (kk & 7));
}
__device__ __forceinline__ int ps_idx(int r, int c) {
  return r * 64 + ((((c >> 3) ^ ((r >> 2) & 7)) << 3) | (c & 7));
}

__global__ __launch_bounds__(256, 2) void attn_fwd(const u16* __restrict__ qkv,
                                                   u16* __restrict__ ctx) {
  constexpr int NQ = 6144, SD = 2048;
  __shared__ __attribute__((aligned(16))) u16 Ks[2][64 * 128];
  __shared__ __attribute__((aligned(16))) u16 Vt[2][128 * 64];
  __shared__ __attribute__((aligned(16))) u16 Ps[128 * 64];
  const int t = threadIdx.x, lane = t & 63, w = t >> 6;
  const int l15 = lane & 15, l4 = lane >> 4;
  const int h = blockIdx.y, b = blockIdx.z;
  const size_t rowbase = (size_t)b * 2048;
  const int hq = h * 384;

  const u16* Kg = qkv + (rowbase + (t >> 4)) * NQ + hq + 128 +
                  (((t & 15) ^ ((t >> 4) & 7)) << 3);
  const u16* Vg = qkv + (rowbase + (t & 15)) * NQ + hq + 256 + ((t >> 4) << 3);
  const int vkk = t & 15, vd0 = (t >> 4) << 3;

  const float C = 0.12751879522447905f;   // (1/sqrt(128)) * log2(e)
  const float THRC = 62.73592239488341f;  // 8 / C

  for (int seg = 0; seg < 2; ++seg) {
    const int qt = (seg == 0) ? (15 - (int)blockIdx.x) : (int)blockIdx.x;
    const int q0 = qt * 128;
    const int nt = 2 * qt + 2;
    const int qr0 = q0 + w * 32 + l4 * 4;  // + mi*16 + r

    bf16x8 qf[2][4];
#pragma unroll
    for (int mi = 0; mi < 2; ++mi) {
      const u16* qp =
          qkv + (rowbase + q0 + w * 32 + mi * 16 + l15) * NQ + hq + l4 * 8;
#pragma unroll
      for (int kc = 0; kc < 4; ++kc) qf[mi][kc] = *(const bf16x8*)(qp + kc * 32);
    }

    f32x4 z4 = {0.f, 0.f, 0.f, 0.f};
    f32x4 oacc[2][8];
#pragma unroll
    for (int mi = 0; mi < 2; ++mi)
#pragma unroll
      for (int i = 0; i < 8; ++i) oacc[mi][i] = z4;
    float m_run[2][4], l_run[2][4];
#pragma unroll
    for (int mi = 0; mi < 2; ++mi)
#pragma unroll
      for (int r = 0; r < 4; ++r) { m_run[mi][r] = -3.0e38f; l_run[mi][r] = 0.f; }

    u16x8 vA[4], vB[4];
#pragma unroll
    for (int i = 0; i < 4; ++i)
      GLDS16(Kg + (size_t)(i * 16) * NQ, &Ks[0][i * 2048 + w * 512]);
#pragma unroll
    for (int p = 0; p < 4; ++p)
      vA[p] = *(const u16x8*)(Vg + (size_t)(p * 16) * NQ);
    __syncthreads();
#pragma unroll
    for (int p = 0; p < 4; ++p) {
      int kk = p * 16 + vkk;
#pragma unroll
      for (int j = 0; j < 8; ++j) Vt[0][vt_idx(vd0 + j, kk)] = vA[p][j];
    }
#pragma unroll
    for (int p = 0; p < 4; ++p)
      vA[p] = *(const u16x8*)(Vg + (size_t)(64 + p * 16) * NQ);
    __syncthreads();

    for (int tt = 0; tt < nt; ++tt) {
      const int k0 = tt * 64, cur = tt & 1;
      const int kn = (k0 + 64 < q0 + 64) ? k0 + 64 : q0 + 64;
#pragma unroll
      for (int i = 0; i < 4; ++i)
        GLDS16(Kg + (size_t)(kn + i * 16) * NQ,
               &Ks[cur ^ 1][i * 2048 + w * 512]);
      const int kv = (k0 + 128 < q0 + 64) ? k0 + 128 : q0 + 64;
#pragma unroll
      for (int p = 0; p < 4; ++p)
        vB[p] = *(const u16x8*)(Vg + (size_t)(kv + p * 16) * NQ);

      // S = Q K^T
      f32x4 sc[2][4];
#pragma unroll
      for (int mi = 0; mi < 2; ++mi)
#pragma unroll
        for (int nf = 0; nf < 4; ++nf) sc[mi][nf] = z4;
#pragma unroll
      for (int kc = 0; kc < 4; ++kc)
#pragma unroll
        for (int nf = 0; nf < 4; ++nf) {
          int rk = nf * 16 + l15;
          bf16x8 kf = *(const bf16x8*)(&Ks[cur][rk * 128 +
                                              (((kc * 4 + l4) ^ (rk & 7)) << 3)]);
          sc[0][nf] = mfma_bf16(qf[0][kc], kf, sc[0][nf]);
          sc[1][nf] = mfma_bf16(qf[1][kc], kf, sc[1][nf]);
        }
      if (tt + 2 >= nt) {
#pragma unroll
        for (int mi = 0; mi < 2; ++mi)
#pragma unroll
          for (int nf = 0; nf < 4; ++nf) {
            int col = k0 + nf * 16 + l15;
            int qr = qr0 + mi * 16;
#pragma unroll
            for (int r = 0; r < 4; ++r)
              if (col > qr + r) sc[mi][nf][r] = -3.0e38f;
          }
      }
      // row max over 16 col-lanes (DPP, VALU-only)
      float mx[2][4];
#pragma unroll
      for (int mi = 0; mi < 2; ++mi)
#pragma unroll
        for (int r = 0; r < 4; ++r)
          mx[mi][r] = dpp_max16(fmaxf(fmaxf(sc[mi][0][r], sc[mi][1][r]),
                                      fmaxf(sc[mi][2][r], sc[mi][3][r])));
      bool upd = false;
#pragma unroll
      for (int mi = 0; mi < 2; ++mi)
#pragma unroll
        for (int r = 0; r < 4; ++r)
          upd |= (mx[mi][r] > m_run[mi][r] + THRC);
      if (__any(upd)) {
#pragma unroll
        for (int mi = 0; mi < 2; ++mi)
#pragma unroll
          for (int r = 0; r < 4; ++r) {
            float mn = fmaxf(m_run[mi][r], mx[mi][r]);
            float cr = exp2f((m_run[mi][r] - mn) * C);
            m_run[mi][r] = mn;
            l_run[mi][r] *= cr;
#pragma unroll
            for (int nf = 0; nf < 8; ++nf) oacc[mi][nf][r] *= cr;
          }
      }
#pragma unroll
      for (int mi = 0; mi < 2; ++mi) {
        float mC[4], sm[4];
#pragma unroll
        for (int r = 0; r < 4; ++r) mC[r] = m_run[mi][r] * C;
#pragma unroll
        for (int nf = 0; nf < 4; ++nf)
#pragma unroll
          for (int r = 0; r < 4; ++r)
            sc[mi][nf][r] = exp2f(fmaf(sc[mi][nf][r], C, -mC[r]));
#pragma unroll
        for (int r = 0; r < 4; ++r)
          sm[r] = dpp_sum16((sc[mi][0][r] + sc[mi][1][r]) +
                            (sc[mi][2][r] + sc[mi][3][r]));
#pragma unroll
        for (int r = 0; r < 4; ++r) l_run[mi][r] += sm[r];
#pragma unroll
        for (int nf = 0; nf < 4; ++nf)
#pragma unroll
          for (int r = 0; r < 4; ++r)
            ((__bf16*)Ps)[ps_idx(w * 32 + mi * 16 + l4 * 4 + r,
                                 nf * 16 + l15)] = (__bf16)sc[mi][nf][r];
      }
#pragma unroll
      for (int p = 0; p < 4; ++p) {
        int kk = p * 16 + vkk;
#pragma unroll
        for (int j = 0; j < 8; ++j) Vt[cur ^ 1][vt_idx(vd0 + j, kk)] = vA[p][j];
      }
      // O += P V
#pragma unroll
      for (int kc = 0; kc < 2; ++kc) {
        bf16x8 pf0 =
            *(const bf16x8*)(Ps + ps_idx(w * 32 + l15, kc * 32 + l4 * 8));
        bf16x8 pf1 =
            *(const bf16x8*)(Ps + ps_idx(w * 32 + 16 + l15, kc * 32 + l4 * 8));
#pragma unroll
        for (int nf = 0; nf < 8; ++nf) {
          bf16x8 vf = *(const bf16x8*)(&Vt[cur][vt_idx(nf * 16 + l15,
                                                       kc * 32 + l4 * 8)]);
          oacc[0][nf] = mfma_bf16(pf0, vf, oacc[0][nf]);
          oacc[1][nf] = mfma_bf16(pf1, vf, oacc[1][nf]);
        }
      }
      __syncthreads();
#pragma unroll
      for (int p = 0; p < 4; ++p) vA[p] = vB[p];
    }
#pragma unroll
    for (int mi = 0; mi < 2; ++mi) {
      float inv[4];
#pragma unroll
      for (int r = 0; r < 4; ++r) inv[r] = 1.f / l_run[mi][r];
      u16* cp = ctx + (rowbase + q0 + w * 32 + mi * 16 + l4 * 4) * SD +
                h * 128 + l15;
#pragma unroll
      for (int nf = 0; nf < 8; ++nf)
#pragma unroll
        for (int r = 0; r < 4; ++r)
          ((__bf16*)cp)[(size_t)r * SD + nf * 16] =
              (__bf16)(oacc[mi][nf][r] * inv[r]);
    }
  }
}

// ----------------------------------------------------------------- launch
extern "C" void kernel_launch(void* const* d_in, const int* in_sizes, int n_in,
                              void* d_out, int out_size, void* d_ws,
                              size_t ws_size, hipStream_t stream) {
  const float* x = (const float*)d_in[0];
  const float* wqkv = (const float*)d_in[2];
  const float* bqkv = (const float*)d_in[3];
  const float* wout = (const float*)d_in[4];
  const float* bout = (const float*)d_in[5];
  float* out = (float*)d_out;
  char* ws = (char*)d_ws;

  u16* xb = (u16*)(ws);                  //  33,554,432  x bf16 (later: ctx)
  u16* wqkvb = (u16*)(ws + 33554432);    //  25,165,824  w_qkv bf16
  u16* woutb = (u16*)(ws + 58720256);    //   8,388,608  w_out bf16
  u16* qkvb = (u16*)(ws + 67108864);     // 100,663,296  qkv bf16
  u16* ctx = xb;                         // reuse (x dead after gemm1)

  cvt_f32_bf16<<<2048, 256, 0, stream>>>(x, xb, 16777216 / 8);
  cvt_f32_bf16<<<2048, 256, 0, stream>>>(wqkv, wqkvb, 12582912 / 8);
  cvt_f32_bf16<<<1024, 256, 0, stream>>>(wout, woutb, 4194304 / 8);
  gemm8p<1><<<dim3(32 * 24), 512, 0, stream>>>(xb, wqkvb, bqkv, qkvb, 8192,
                                               6144, 2048, 32);
  attn_fwd<<<dim3(8, 16, 4), 256, 0, stream>>>(qkvb, ctx);
  gemm8p<0><<<dim3(32 * 8), 512, 0, stream>>>(ctx, woutb, bout, out, 8192,
                                              2048, 2048, 32);
}